// Round 7
// baseline (392.672 us; speedup 1.0000x reference)
//
#include <hip/hip_runtime.h>
#include <math.h>

#define SS 2048
#define DD 1280
#define HH 16
#define HDD 80
#define ND3 3840

typedef __attribute__((ext_vector_type(8))) short short8;
typedef __attribute__((ext_vector_type(4))) short s16x4;
typedef __attribute__((ext_vector_type(4))) float f32x4;

__device__ inline short f2bf(float f) {
    union { float f; unsigned u; } x; x.f = f;
    unsigned r = x.u + 0x7FFF + ((x.u >> 16) & 1);
    return (short)(r >> 16);
}
__device__ inline float bf2f(short s) {
    union { unsigned u; float f; } x; x.u = ((unsigned)(unsigned short)s) << 16;
    return x.f;
}

// ---------------- fused split: fp32 arrays -> (hi, lo) bf16 ----------------
__global__ __launch_bounds__(256) void split3(
    const float* __restrict__ a, short* __restrict__ ah, short* __restrict__ al, int nbA,
    const float* __restrict__ b, short* __restrict__ bh, short* __restrict__ bl, int nbB,
    const float* __restrict__ c, short* __restrict__ ch, short* __restrict__ cl)
{
    const float* x; short* h; short* l;
    int blk = blockIdx.x;
    if (blk < nbA)            { x = a; h = ah; l = al; }
    else if (blk < nbA + nbB) { blk -= nbA; x = b; h = bh; l = bl; }
    else                      { blk -= nbA + nbB; x = c; h = ch; l = cl; }
    int i = (blk * 256 + threadIdx.x) * 4;
    float4 v = *(const float4*)(x + i);
    s16x4 hv, lv;
    float vv[4] = {v.x, v.y, v.z, v.w};
    #pragma unroll
    for (int t = 0; t < 4; ++t) {
        short hh = f2bf(vv[t]);
        hv[t] = hh;
        lv[t] = f2bf(vv[t] - bf2f(hh));
    }
    *(s16x4*)(h + i) = hv;
    *(s16x4*)(l + i) = lv;
}

// ------- bf16x3 MFMA GEMM: A via LDS, B fragments direct from global -------
// C = A @ B^T + bias. Tile BMT x BNT (BMT=64), 4 waves in 2x2.
// Per wave: IT=BMT/32 m-frags via LDS, JT=BNT/32 n-frags via global_load_dwordx4
// (per-lane 16B at row*K — L2-served, no LDS, no barrier dependency).
// grid: x = m-panel (fast), y = n-panel -> consecutive blocks share B panel (L2).
#define LDSA(m, kg) ((m) * 32 + (((kg) ^ (((m) >> 1) & 3)) << 3))

template <int BMT, int BNT>
__global__ __launch_bounds__(256) void gemm_ablds_bg(
    const short* __restrict__ Ah, const short* __restrict__ Al,
    const short* __restrict__ Bh, const short* __restrict__ Bl,
    const float* __restrict__ bias, float* __restrict__ C,
    int M, int N, int K)
{
    constexpr int IT = BMT / 32;   // m-frags per wave
    constexpr int JT = BNT / 32;   // n-frags per wave
    __shared__ short AhS[BMT * 32];
    __shared__ short AlS[BMT * 32];

    const int tid = threadIdx.x;
    const int w = tid >> 6;
    const int lane = tid & 63;
    const int l15 = lane & 15;
    const int quad = lane >> 4;
    const int wm = w >> 1, wn = w & 1;
    const int bm = blockIdx.x * BMT;
    const int bn = blockIdx.y * BNT;

    f32x4 acc[IT][JT];
    #pragma unroll
    for (int i = 0; i < IT; ++i)
        #pragma unroll
        for (int j = 0; j < JT; ++j)
            acc[i][j] = (f32x4){0.f, 0.f, 0.f, 0.f};

    // per-lane B row pointers (advance 32 shorts per k-step)
    const short* bph[JT];
    const short* bpl[JT];
    #pragma unroll
    for (int j = 0; j < JT; ++j) {
        int col = bn + wn * (BNT / 2) + j * 16 + l15;
        bph[j] = Bh + (size_t)col * K + quad * 8;
        bpl[j] = Bl + (size_t)col * K + quad * 8;
    }

    // A staging: BMT*32 shorts per array; 256 threads x (BMT/64) short8 chunks
    constexpr int AU = BMT / 64;
    short8 rah[AU], ral[AU];
    auto loadA = [&](int k0) {
        #pragma unroll
        for (int u = 0; u < AU; ++u) {
            int c = tid + u * 256, m = c >> 2, kg = c & 3;
            size_t off = (size_t)(bm + m) * K + k0 + kg * 8;
            rah[u] = *(const short8*)(Ah + off);
            ral[u] = *(const short8*)(Al + off);
        }
    };

    loadA(0);
    for (int k0 = 0; k0 < K; k0 += 32) {
        // B fragments for this step: pure global, no barrier dependency
        short8 bfh[JT], bfl[JT];
        #pragma unroll
        for (int j = 0; j < JT; ++j) {
            bfh[j] = *(const short8*)(bph[j] + k0);
            bfl[j] = *(const short8*)(bpl[j] + k0);
        }
        __syncthreads();
        #pragma unroll
        for (int u = 0; u < AU; ++u) {
            int c = tid + u * 256, m = c >> 2, kg = c & 3;
            *(short8*)&AhS[LDSA(m, kg)] = rah[u];
            *(short8*)&AlS[LDSA(m, kg)] = ral[u];
        }
        __syncthreads();
        if (k0 + 32 < K) loadA(k0 + 32);

        short8 af[IT], alf[IT];
        #pragma unroll
        for (int i = 0; i < IT; ++i) {
            int m = wm * (BMT / 2) + i * 16 + l15;
            af[i]  = *(short8*)&AhS[LDSA(m, quad)];
            alf[i] = *(short8*)&AlS[LDSA(m, quad)];
        }
        #pragma unroll
        for (int i = 0; i < IT; ++i)
            #pragma unroll
            for (int j = 0; j < JT; ++j) {
                acc[i][j] = __builtin_amdgcn_mfma_f32_16x16x32_bf16(af[i],  bfh[j], acc[i][j], 0, 0, 0);
                acc[i][j] = __builtin_amdgcn_mfma_f32_16x16x32_bf16(af[i],  bfl[j], acc[i][j], 0, 0, 0);
                acc[i][j] = __builtin_amdgcn_mfma_f32_16x16x32_bf16(alf[i], bfh[j], acc[i][j], 0, 0, 0);
            }
    }

    #pragma unroll
    for (int j = 0; j < JT; ++j) {
        int col = bn + wn * (BNT / 2) + j * 16 + l15;
        float bb = bias[col];
        #pragma unroll
        for (int i = 0; i < IT; ++i)
            #pragma unroll
            for (int r = 0; r < 4; ++r) {
                int row = bm + wm * (BMT / 2) + i * 16 + quad * 4 + r;
                C[(size_t)row * N + col] = acc[i][j][r] + bb;
            }
    }
}

// ---------------- RoPE + scatter -> bf16 q (pre-scaled), k, v ----------------
__global__ __launch_bounds__(256) void rope_scatter_bf16(
    const float* __restrict__ qkv, const float* __restrict__ rpe,
    short* __restrict__ q, short* __restrict__ k, short* __restrict__ v)
{
    __shared__ float cs[40], sn[40];
    const int s = blockIdx.x;
    if (threadIdx.x < 40)
        __sincosf(rpe[s * 40 + threadIdx.x], &sn[threadIdx.x], &cs[threadIdx.x]);
    __syncthreads();
    const float scale = 0.11180339887498949f;  // 80^-0.5
    for (int j = threadIdx.x; j < ND3; j += 256) {
        int p = j / DD;
        int rem = j - p * DD;
        int hh = rem / HDD;
        int d = rem - hh * HDD;
        float x = qkv[(size_t)s * ND3 + j];
        float val;
        if (p == 2) {
            val = x;
        } else {
            int dm = (d < 40) ? d : d - 40;
            float other = (d < 40)
                ? -qkv[(size_t)s * ND3 + p * DD + hh * HDD + d + 40]
                :  qkv[(size_t)s * ND3 + p * DD + hh * HDD + d - 40];
            val = x * cs[dm] + other * sn[dm];
            if (p == 0) val *= scale;
        }
        short* dst = (p == 0) ? q : (p == 1) ? k : v;
        dst[((size_t)hh * SS + s) * HDD + d] = f2bf(val);
    }
}

// ---------------- flash attention, bf16 MFMA, fixed-max softmax, K-split ------
__global__ __launch_bounds__(256) void attn_mfma(
    const short* __restrict__ q, const short* __restrict__ k,
    const short* __restrict__ v, float* __restrict__ o_part,
    float* __restrict__ l_part)
{
    __shared__ short Ks[64][104];
    __shared__ short Vts[80][72];
    __shared__ short Ps[4][16][72];

    const int h = blockIdx.y;
    const int q0 = blockIdx.x << 6;
    const int z = blockIdx.z;
    const int tid = threadIdx.x;
    const int w = tid >> 6;
    const int lane = tid & 63;
    const int l15 = lane & 15;
    const int quad = lane >> 4;

    const short* qbase = q + (size_t)h * SS * HDD;
    const short* kbase = k + (size_t)h * SS * HDD;
    const short* vbase = v + (size_t)h * SS * HDD;

    short8 qf[3];
    {
        const int row = q0 + w * 16 + l15;
        #pragma unroll
        for (int kk = 0; kk < 3; ++kk) {
            int c0 = kk * 32 + quad * 8;
            qf[kk] = (c0 < HDD) ? *(const short8*)(qbase + (size_t)row * HDD + c0)
                                : (short8)0;
        }
    }

    if (tid < 128) {
        int r = tid >> 1, c = 80 + (tid & 1) * 8;
        *(short8*)&Ks[r][c] = (short8)0;
    }

    float lsum[4] = {0.f, 0.f, 0.f, 0.f};
    f32x4 o[5];
    #pragma unroll
    for (int n = 0; n < 5; ++n) o[n] = (f32x4){0.f, 0.f, 0.f, 0.f};

    const int kt0 = z << 10;
    for (int kt = kt0; kt < kt0 + 1024; kt += 64) {
        __syncthreads();
        #pragma unroll
        for (int u = 0; u < 3; ++u) {
            int i = tid + u * 256;
            if (i < 640) {
                int r = i / 10, c = (i - r * 10) * 8;
                *(short8*)&Ks[r][c] = *(const short8*)(kbase + (size_t)(kt + r) * HDD + c);
            }
        }
        #pragma unroll
        for (int u = 0; u < 2; ++u) {
            int task = tid + u * 256;
            if (task < 320) {
                int r4 = (task & 15) << 2, d4 = (task >> 4) << 2;
                s16x4 a0 = *(const s16x4*)(vbase + (size_t)(kt + r4 + 0) * HDD + d4);
                s16x4 a1 = *(const s16x4*)(vbase + (size_t)(kt + r4 + 1) * HDD + d4);
                s16x4 a2 = *(const s16x4*)(vbase + (size_t)(kt + r4 + 2) * HDD + d4);
                s16x4 a3 = *(const s16x4*)(vbase + (size_t)(kt + r4 + 3) * HDD + d4);
                #pragma unroll
                for (int j = 0; j < 4; ++j) {
                    s16x4 w4 = {a0[j], a1[j], a2[j], a3[j]};
                    *(s16x4*)&Vts[d4 + j][r4] = w4;
                }
            }
        }
        __syncthreads();

        f32x4 s_[4];
        #pragma unroll
        for (int nt = 0; nt < 4; ++nt) {
            f32x4 acc = (f32x4){0.f, 0.f, 0.f, 0.f};
            #pragma unroll
            for (int kk = 0; kk < 3; ++kk) {
                short8 bf = *(short8*)&Ks[nt * 16 + l15][kk * 32 + quad * 8];
                acc = __builtin_amdgcn_mfma_f32_16x16x32_bf16(qf[kk], bf, acc, 0, 0, 0);
            }
            s_[nt] = acc;
        }

        #pragma unroll
        for (int nt = 0; nt < 4; ++nt)
            #pragma unroll
            for (int r = 0; r < 4; ++r) {
                float p = __expf(s_[nt][r] - 16.f);
                lsum[r] += p;
                Ps[w][quad * 4 + r][nt * 16 + l15] = f2bf(p);
            }

        short8 pf[2];
        #pragma unroll
        for (int kk = 0; kk < 2; ++kk)
            pf[kk] = *(short8*)&Ps[w][l15][kk * 32 + quad * 8];
        #pragma unroll
        for (int n = 0; n < 5; ++n)
            #pragma unroll
            for (int kk = 0; kk < 2; ++kk) {
                short8 vf = *(short8*)&Vts[n * 16 + l15][kk * 32 + quad * 8];
                o[n] = __builtin_amdgcn_mfma_f32_16x16x32_bf16(pf[kk], vf, o[n], 0, 0, 0);
            }
    }

    #pragma unroll
    for (int r = 0; r < 4; ++r) {
        float rs = lsum[r];
        #pragma unroll
        for (int off = 1; off < 16; off <<= 1)
            rs += __shfl_xor(rs, off, 64);
        lsum[r] = rs;
    }

    float* ob = o_part + (size_t)z * SS * DD;
    #pragma unroll
    for (int n = 0; n < 5; ++n)
        #pragma unroll
        for (int r = 0; r < 4; ++r) {
            int row = q0 + w * 16 + quad * 4 + r;
            ob[(size_t)row * DD + h * HDD + n * 16 + l15] = o[n][r];
        }
    if (l15 == 0)
        #pragma unroll
        for (int r = 0; r < 4; ++r)
            l_part[((size_t)z * HH + h) * SS + q0 + w * 16 + quad * 4 + r] = lsum[r];
}

// ---------------- merge K-split halves, emit hi/lo bf16 ----------------
__global__ __launch_bounds__(256) void attn_merge(
    const float* __restrict__ o_part, const float* __restrict__ l_part,
    short* __restrict__ hi, short* __restrict__ lo)
{
    int i = (blockIdx.x * 256 + threadIdx.x) * 4;
    int row = i / DD;
    int col = i - row * DD;
    int h = col / HDD;
    float4 a = *(const float4*)(o_part + i);
    float4 b = *(const float4*)(o_part + (size_t)SS * DD + i);
    float l = l_part[h * SS + row] + l_part[(HH + h) * SS + row];
    float inv = 1.f / l;
    float vv[4] = {a.x + b.x, a.y + b.y, a.z + b.z, a.w + b.w};
    s16x4 vh, vl;
    #pragma unroll
    for (int c = 0; c < 4; ++c) {
        float ov = vv[c] * inv;
        short hh = f2bf(ov);
        vh[c] = hh;
        vl[c] = f2bf(ov - bf2f(hh));
    }
    *(s16x4*)(hi + i) = vh;
    *(s16x4*)(lo + i) = vl;
}

extern "C" void kernel_launch(void* const* d_in, const int* in_sizes, int n_in,
                              void* d_out, int out_size, void* d_ws, size_t ws_size,
                              hipStream_t stream)
{
    const float* hs     = (const float*)d_in[0];
    const float* rpe    = (const float*)d_in[1];
    const float* qkv_w  = (const float*)d_in[2];
    const float* qkv_b  = (const float*)d_in[3];
    const float* proj_w = (const float*)d_in[4];
    const float* proj_b = (const float*)d_in[5];
    float* out = (float*)d_out;

    // ---- workspace layout (61.4 MB, region-aliased) ----
    short* s0 = (short*)d_ws;                 // R0: 15,728,640 shorts = 7,864,320 floats
    float* qkv_f  = (float*)d_ws;             //   [S][3D] fp32, dead after rope
    float* o_part = (float*)d_ws;             //   R0 reuse after rope: 2 x S x D partial O
    float* l_part = (float*)d_ws + 5242880;   //   2 x H x S partial l
    short* s1 = s0 + 15728640;                // R1: 9,830,400 shorts
    short* qkvw_hi = s1;                      //   dead after gemm1
    short* qkvw_lo = s1 + 4915200;
    short* qb = s1;                           //   R1 reuse after gemm1
    short* kb = s1 + 2621440;
    short* vb = s1 + 5242880;
    short* attn_hi = s1;                      //   R1 reuse after attn
    short* attn_lo = s1 + 2621440;
    short* s2 = s1 + 9830400;                 // R2: 5,242,880 shorts
    short* hs_hi = s2;                        //   dead after gemm1
    short* hs_lo = s2 + 2621440;
    short* projw_hi = s2;                     //   R2 reuse after gemm1
    short* projw_lo = s2 + 1638400;

    const int n_hs = SS * DD;        // 2,621,440 -> 2560 blocks
    const int n_qw = ND3 * DD;       // 4,915,200 -> 4800 blocks
    const int n_pw = DD * DD;        // 1,638,400 -> 1600 blocks

    split3<<<n_hs / 1024 + n_qw / 1024, 256, 0, stream>>>(
        hs, hs_hi, hs_lo, n_hs / 1024,
        qkv_w, qkvw_hi, qkvw_lo, n_qw / 1024,
        qkv_w, qkvw_hi, qkvw_lo);   // third slot unused
    // QKV GEMM: 64x128 tiles, A-LDS/B-global, grid (32, 30) = 960 blocks
    gemm_ablds_bg<64, 128><<<dim3(SS / 64, ND3 / 128), 256, 0, stream>>>(
        hs_hi, hs_lo, qkvw_hi, qkvw_lo, qkv_b, qkv_f, SS, ND3, DD);
    // proj_w split into R2 (hs hi/lo dead after gemm1)
    split3<<<n_pw / 1024, 256, 0, stream>>>(
        proj_w, projw_hi, projw_lo, n_pw / 1024,
        proj_w, projw_hi, projw_lo, 0,
        proj_w, projw_hi, projw_lo);
    rope_scatter_bf16<<<SS, 256, 0, stream>>>(qkv_f, rpe, qb, kb, vb);
    attn_mfma<<<dim3(SS / 64, HH, 2), 256, 0, stream>>>(qb, kb, vb, o_part, l_part);
    attn_merge<<<(SS * DD) / 1024, 256, 0, stream>>>(o_part, l_part, attn_hi, attn_lo);
    // proj GEMM: 64x64 tiles, grid (32, 20) = 640 blocks
    gemm_ablds_bg<64, 64><<<dim3(SS / 64, DD / 64), 256, 0, stream>>>(
        attn_hi, attn_lo, projw_hi, projw_lo, proj_b, out, SS, DD, DD);
}

// Round 8
// 218.758 us; speedup vs baseline: 1.7950x; 1.7950x over previous
//
#include <hip/hip_runtime.h>
#include <math.h>

#define SS 2048
#define DD 1280
#define HH 16
#define HDD 80
#define ND3 3840

typedef __attribute__((ext_vector_type(8))) short short8;
typedef __attribute__((ext_vector_type(4))) short s16x4;
typedef __attribute__((ext_vector_type(4))) float f32x4;
typedef __attribute__((ext_vector_type(8))) _Float16 h16x8;
typedef __attribute__((ext_vector_type(4))) _Float16 h16x4;

__device__ inline short f2bf(float f) {
    union { float f; unsigned u; } x; x.f = f;
    unsigned r = x.u + 0x7FFF + ((x.u >> 16) & 1);
    return (short)(r >> 16);
}

// ---------------- fused convert: fp32 arrays -> fp16 ----------------
__global__ __launch_bounds__(256) void split_f16(
    const float* __restrict__ a, _Float16* __restrict__ ah, int nbA,
    const float* __restrict__ b, _Float16* __restrict__ bh, int nbB,
    const float* __restrict__ c, _Float16* __restrict__ ch)
{
    const float* x; _Float16* h;
    int blk = blockIdx.x;
    if (blk < nbA)            { x = a; h = ah; }
    else if (blk < nbA + nbB) { blk -= nbA; x = b; h = bh; }
    else                      { blk -= nbA + nbB; x = c; h = ch; }
    int i = (blk * 256 + threadIdx.x) * 4;
    float4 v = *(const float4*)(x + i);
    h16x4 hv;
    hv[0] = (_Float16)v.x; hv[1] = (_Float16)v.y;
    hv[2] = (_Float16)v.z; hv[3] = (_Float16)v.w;
    *(h16x4*)(h + i) = hv;
}

// ---------------- fp16 MFMA GEMM: C = A @ B^T + bias (R4-proven structure) ----
// Tile BMT x BNT, 4 waves (2x2), BK=32, both operands LDS-staged, swizzled,
// register-prefetched global loads, plain-store epilogue.
#define LDSA(m, kg) ((m) * 32 + (((kg) ^ (((m) >> 1) & 3)) << 3))

template <int BMT, int BNT>
__global__ __launch_bounds__(256) void gemm_f16(
    const _Float16* __restrict__ Ah, const _Float16* __restrict__ Bh,
    const float* __restrict__ bias, float* __restrict__ C,
    int M, int N, int K)
{
    constexpr int IT = BMT / 32;        // m-frags per wave
    constexpr int JT = BNT / 32;        // n-frags per wave
    constexpr int AU = BMT / 64;        // A staging chunks per thread
    constexpr int BU = BNT / 64;        // B staging chunks per thread
    __shared__ _Float16 AhS[BMT * 32];
    __shared__ _Float16 BhS[BNT * 32];

    const int tid = threadIdx.x;
    const int w = tid >> 6;
    const int lane = tid & 63;
    const int l15 = lane & 15;
    const int quad = lane >> 4;
    const int wm = w >> 1, wn = w & 1;
    const int bm = blockIdx.y * BMT;
    const int bn = blockIdx.x * BNT;

    f32x4 acc[IT][JT];
    #pragma unroll
    for (int i = 0; i < IT; ++i)
        #pragma unroll
        for (int j = 0; j < JT; ++j)
            acc[i][j] = (f32x4){0.f, 0.f, 0.f, 0.f};

    h16x8 rah[AU], rbh[BU];
    auto loadg = [&](int k0) {
        #pragma unroll
        for (int u = 0; u < AU; ++u) {
            int c = tid + u * 256, m = c >> 2, kg = c & 3;
            rah[u] = *(const h16x8*)(Ah + (size_t)(bm + m) * K + k0 + kg * 8);
        }
        #pragma unroll
        for (int u = 0; u < BU; ++u) {
            int c = tid + u * 256, m = c >> 2, kg = c & 3;
            rbh[u] = *(const h16x8*)(Bh + (size_t)(bn + m) * K + k0 + kg * 8);
        }
    };

    loadg(0);
    for (int k0 = 0; k0 < K; k0 += 32) {
        __syncthreads();
        #pragma unroll
        for (int u = 0; u < AU; ++u) {
            int c = tid + u * 256, m = c >> 2, kg = c & 3;
            *(h16x8*)&AhS[LDSA(m, kg)] = rah[u];
        }
        #pragma unroll
        for (int u = 0; u < BU; ++u) {
            int c = tid + u * 256, m = c >> 2, kg = c & 3;
            *(h16x8*)&BhS[LDSA(m, kg)] = rbh[u];
        }
        __syncthreads();
        if (k0 + 32 < K) loadg(k0 + 32);

        h16x8 af[IT], bf[JT];
        #pragma unroll
        for (int i = 0; i < IT; ++i) {
            int m = wm * (BMT / 2) + i * 16 + l15;
            af[i] = *(h16x8*)&AhS[LDSA(m, quad)];
        }
        #pragma unroll
        for (int j = 0; j < JT; ++j) {
            int n = wn * (BNT / 2) + j * 16 + l15;
            bf[j] = *(h16x8*)&BhS[LDSA(n, quad)];
        }
        #pragma unroll
        for (int i = 0; i < IT; ++i)
            #pragma unroll
            for (int j = 0; j < JT; ++j)
                acc[i][j] = __builtin_amdgcn_mfma_f32_16x16x32_f16(af[i], bf[j], acc[i][j], 0, 0, 0);
    }

    #pragma unroll
    for (int j = 0; j < JT; ++j) {
        int col = bn + wn * (BNT / 2) + j * 16 + l15;
        float bb = bias[col];
        #pragma unroll
        for (int i = 0; i < IT; ++i)
            #pragma unroll
            for (int r = 0; r < 4; ++r) {
                int row = bm + wm * (BMT / 2) + i * 16 + quad * 4 + r;
                C[(size_t)row * N + col] = acc[i][j][r] + bb;
            }
    }
}

// ---------------- RoPE + scatter -> bf16 q (pre-scaled), k, v ----------------
__global__ __launch_bounds__(256) void rope_scatter_bf16(
    const float* __restrict__ qkv, const float* __restrict__ rpe,
    short* __restrict__ q, short* __restrict__ k, short* __restrict__ v)
{
    __shared__ float cs[40], sn[40];
    const int s = blockIdx.x;
    if (threadIdx.x < 40)
        __sincosf(rpe[s * 40 + threadIdx.x], &sn[threadIdx.x], &cs[threadIdx.x]);
    __syncthreads();
    const float scale = 0.11180339887498949f;  // 80^-0.5
    for (int j = threadIdx.x; j < ND3; j += 256) {
        int p = j / DD;
        int rem = j - p * DD;
        int hh = rem / HDD;
        int d = rem - hh * HDD;
        float x = qkv[(size_t)s * ND3 + j];
        float val;
        if (p == 2) {
            val = x;
        } else {
            int dm = (d < 40) ? d : d - 40;
            float other = (d < 40)
                ? -qkv[(size_t)s * ND3 + p * DD + hh * HDD + d + 40]
                :  qkv[(size_t)s * ND3 + p * DD + hh * HDD + d - 40];
            val = x * cs[dm] + other * sn[dm];
            if (p == 0) val *= scale;
        }
        short* dst = (p == 0) ? q : (p == 1) ? k : v;
        dst[((size_t)hh * SS + s) * HDD + d] = f2bf(val);
    }
}

// ---------------- flash attention, bf16 MFMA, fixed-max softmax, K-split ------
__global__ __launch_bounds__(256) void attn_mfma(
    const short* __restrict__ q, const short* __restrict__ k,
    const short* __restrict__ v, float* __restrict__ o_part,
    float* __restrict__ l_part)
{
    __shared__ short Ks[64][104];
    __shared__ short Vts[80][72];
    __shared__ short Ps[4][16][72];

    const int h = blockIdx.y;
    const int q0 = blockIdx.x << 6;
    const int z = blockIdx.z;
    const int tid = threadIdx.x;
    const int w = tid >> 6;
    const int lane = tid & 63;
    const int l15 = lane & 15;
    const int quad = lane >> 4;

    const short* qbase = q + (size_t)h * SS * HDD;
    const short* kbase = k + (size_t)h * SS * HDD;
    const short* vbase = v + (size_t)h * SS * HDD;

    short8 qf[3];
    {
        const int row = q0 + w * 16 + l15;
        #pragma unroll
        for (int kk = 0; kk < 3; ++kk) {
            int c0 = kk * 32 + quad * 8;
            qf[kk] = (c0 < HDD) ? *(const short8*)(qbase + (size_t)row * HDD + c0)
                                : (short8)0;
        }
    }

    if (tid < 128) {
        int r = tid >> 1, c = 80 + (tid & 1) * 8;
        *(short8*)&Ks[r][c] = (short8)0;
    }

    float lsum[4] = {0.f, 0.f, 0.f, 0.f};
    f32x4 o[5];
    #pragma unroll
    for (int n = 0; n < 5; ++n) o[n] = (f32x4){0.f, 0.f, 0.f, 0.f};

    const int kt0 = z << 10;
    for (int kt = kt0; kt < kt0 + 1024; kt += 64) {
        __syncthreads();
        #pragma unroll
        for (int u = 0; u < 3; ++u) {
            int i = tid + u * 256;
            if (i < 640) {
                int r = i / 10, c = (i - r * 10) * 8;
                *(short8*)&Ks[r][c] = *(const short8*)(kbase + (size_t)(kt + r) * HDD + c);
            }
        }
        #pragma unroll
        for (int u = 0; u < 2; ++u) {
            int task = tid + u * 256;
            if (task < 320) {
                int r4 = (task & 15) << 2, d4 = (task >> 4) << 2;
                s16x4 a0 = *(const s16x4*)(vbase + (size_t)(kt + r4 + 0) * HDD + d4);
                s16x4 a1 = *(const s16x4*)(vbase + (size_t)(kt + r4 + 1) * HDD + d4);
                s16x4 a2 = *(const s16x4*)(vbase + (size_t)(kt + r4 + 2) * HDD + d4);
                s16x4 a3 = *(const s16x4*)(vbase + (size_t)(kt + r4 + 3) * HDD + d4);
                #pragma unroll
                for (int j = 0; j < 4; ++j) {
                    s16x4 w4 = {a0[j], a1[j], a2[j], a3[j]};
                    *(s16x4*)&Vts[d4 + j][r4] = w4;
                }
            }
        }
        __syncthreads();

        f32x4 s_[4];
        #pragma unroll
        for (int nt = 0; nt < 4; ++nt) {
            f32x4 acc = (f32x4){0.f, 0.f, 0.f, 0.f};
            #pragma unroll
            for (int kk = 0; kk < 3; ++kk) {
                short8 bf = *(short8*)&Ks[nt * 16 + l15][kk * 32 + quad * 8];
                acc = __builtin_amdgcn_mfma_f32_16x16x32_bf16(qf[kk], bf, acc, 0, 0, 0);
            }
            s_[nt] = acc;
        }

        #pragma unroll
        for (int nt = 0; nt < 4; ++nt)
            #pragma unroll
            for (int r = 0; r < 4; ++r) {
                float p = __expf(s_[nt][r] - 16.f);
                lsum[r] += p;
                Ps[w][quad * 4 + r][nt * 16 + l15] = f2bf(p);
            }

        short8 pf[2];
        #pragma unroll
        for (int kk = 0; kk < 2; ++kk)
            pf[kk] = *(short8*)&Ps[w][l15][kk * 32 + quad * 8];
        #pragma unroll
        for (int n = 0; n < 5; ++n)
            #pragma unroll
            for (int kk = 0; kk < 2; ++kk) {
                short8 vf = *(short8*)&Vts[n * 16 + l15][kk * 32 + quad * 8];
                o[n] = __builtin_amdgcn_mfma_f32_16x16x32_bf16(pf[kk], vf, o[n], 0, 0, 0);
            }
    }

    #pragma unroll
    for (int r = 0; r < 4; ++r) {
        float rs = lsum[r];
        #pragma unroll
        for (int off = 1; off < 16; off <<= 1)
            rs += __shfl_xor(rs, off, 64);
        lsum[r] = rs;
    }

    float* ob = o_part + (size_t)z * SS * DD;
    #pragma unroll
    for (int n = 0; n < 5; ++n)
        #pragma unroll
        for (int r = 0; r < 4; ++r) {
            int row = q0 + w * 16 + quad * 4 + r;
            ob[(size_t)row * DD + h * HDD + n * 16 + l15] = o[n][r];
        }
    if (l15 == 0)
        #pragma unroll
        for (int r = 0; r < 4; ++r)
            l_part[((size_t)z * HH + h) * SS + q0 + w * 16 + quad * 4 + r] = lsum[r];
}

// ---------------- merge K-split halves, emit fp16 ----------------
__global__ __launch_bounds__(256) void attn_merge(
    const float* __restrict__ o_part, const float* __restrict__ l_part,
    _Float16* __restrict__ oh)
{
    int i = (blockIdx.x * 256 + threadIdx.x) * 4;
    int row = i / DD;
    int col = i - row * DD;
    int h = col / HDD;
    float4 a = *(const float4*)(o_part + i);
    float4 b = *(const float4*)(o_part + (size_t)SS * DD + i);
    float l = l_part[h * SS + row] + l_part[(HH + h) * SS + row];
    float inv = 1.f / l;
    h16x4 hv;
    hv[0] = (_Float16)((a.x + b.x) * inv);
    hv[1] = (_Float16)((a.y + b.y) * inv);
    hv[2] = (_Float16)((a.z + b.z) * inv);
    hv[3] = (_Float16)((a.w + b.w) * inv);
    *(h16x4*)(oh + i) = hv;
}

extern "C" void kernel_launch(void* const* d_in, const int* in_sizes, int n_in,
                              void* d_out, int out_size, void* d_ws, size_t ws_size,
                              hipStream_t stream)
{
    const float* hs     = (const float*)d_in[0];
    const float* rpe    = (const float*)d_in[1];
    const float* qkv_w  = (const float*)d_in[2];
    const float* qkv_b  = (const float*)d_in[3];
    const float* proj_w = (const float*)d_in[4];
    const float* proj_b = (const float*)d_in[5];
    float* out = (float*)d_out;

    // ---- workspace layout (52.4 MB, region-aliased; 2-byte units) ----
    short* s0 = (short*)d_ws;                 // R0: 15,728,640 units
    float* qkv_f  = (float*)d_ws;             //   [S][3D] fp32, dead after rope
    float* o_part = (float*)d_ws;             //   R0 reuse after rope: 2 x S x D
    float* l_part = (float*)d_ws + 5242880;   //   2 x H x S partial l
    short* s1 = s0 + 15728640;                // R1: 7,864,320 units
    _Float16* qkvw_h = (_Float16*)s1;         //   4,915,200 (dead after gemm1)
    short* qb = s1;                           //   R1 reuse after gemm1
    short* kb = s1 + 2621440;
    short* vb = s1 + 5242880;
    _Float16* attn_h = (_Float16*)s1;         //   R1 reuse after attn (aliases qb)
    short* s2 = s1 + 7864320;                 // R2: 2,621,440 units
    _Float16* hs_h = (_Float16*)s2;           //   dead after gemm1
    _Float16* projw_h = (_Float16*)s2;        //   R2 reuse after gemm1

    const int n_hs = SS * DD;        // 2,621,440 -> 2560 blocks
    const int n_qw = ND3 * DD;       // 4,915,200 -> 4800 blocks
    const int n_pw = DD * DD;        // 1,638,400 -> 1600 blocks

    split_f16<<<n_hs / 1024 + n_qw / 1024, 256, 0, stream>>>(
        hs, hs_h, n_hs / 1024,
        qkv_w, qkvw_h, n_qw / 1024,
        qkv_w, qkvw_h);   // third slot unused
    // QKV GEMM: 128x128 tiles, grid (30, 16) = 480 blocks (R4-proven shape)
    gemm_f16<128, 128><<<dim3(ND3 / 128, SS / 128), 256, 0, stream>>>(
        hs_h, qkvw_h, qkv_b, qkv_f, SS, ND3, DD);
    // proj_w -> fp16 into R2 (hs_h dead after gemm1)
    split_f16<<<n_pw / 1024, 256, 0, stream>>>(
        proj_w, projw_h, n_pw / 1024,
        proj_w, projw_h, 0,
        proj_w, projw_h);
    rope_scatter_bf16<<<SS, 256, 0, stream>>>(qkv_f, rpe, qb, kb, vb);
    attn_mfma<<<dim3(SS / 64, HH, 2), 256, 0, stream>>>(qb, kb, vb, o_part, l_part);
    attn_merge<<<(SS * DD) / 1024, 256, 0, stream>>>(o_part, l_part, attn_h);
    // proj GEMM: 64x128 tiles, grid (10, 32) = 320 blocks
    gemm_f16<64, 128><<<dim3(DD / 128, SS / 64), 256, 0, stream>>>(
        attn_h, projw_h, proj_b, out, SS, DD, DD);
}

// Round 9
// 217.277 us; speedup vs baseline: 1.8072x; 1.0068x over previous
//
#include <hip/hip_runtime.h>
#include <math.h>

#define SS 2048
#define DD 1280
#define HH 16
#define HDD 80
#define ND3 3840

typedef __attribute__((ext_vector_type(8))) short short8;
typedef __attribute__((ext_vector_type(4))) short s16x4;
typedef __attribute__((ext_vector_type(4))) float f32x4;
typedef __attribute__((ext_vector_type(8))) _Float16 h16x8;
typedef __attribute__((ext_vector_type(4))) _Float16 h16x4;

__device__ inline short f2bf(float f) {
    union { float f; unsigned u; } x; x.f = f;
    unsigned r = x.u + 0x7FFF + ((x.u >> 16) & 1);
    return (short)(r >> 16);
}

// ---------------- fused convert: fp32 arrays -> fp16 ----------------
__global__ __launch_bounds__(256) void split_f16(
    const float* __restrict__ a, _Float16* __restrict__ ah, int nbA,
    const float* __restrict__ b, _Float16* __restrict__ bh, int nbB,
    const float* __restrict__ c, _Float16* __restrict__ ch)
{
    const float* x; _Float16* h;
    int blk = blockIdx.x;
    if (blk < nbA)            { x = a; h = ah; }
    else if (blk < nbA + nbB) { blk -= nbA; x = b; h = bh; }
    else                      { blk -= nbA + nbB; x = c; h = ch; }
    int i = (blk * 256 + threadIdx.x) * 4;
    float4 v = *(const float4*)(x + i);
    h16x4 hv;
    hv[0] = (_Float16)v.x; hv[1] = (_Float16)v.y;
    hv[2] = (_Float16)v.z; hv[3] = (_Float16)v.w;
    *(h16x4*)(h + i) = hv;
}

// ---------------- fp16 MFMA GEMM: C = A @ B^T + bias (R8-proven) ----------------
#define LDSA(m, kg) ((m) * 32 + (((kg) ^ (((m) >> 1) & 3)) << 3))

template <int BMT, int BNT>
__global__ __launch_bounds__(256) void gemm_f16(
    const _Float16* __restrict__ Ah, const _Float16* __restrict__ Bh,
    const float* __restrict__ bias, float* __restrict__ C,
    int M, int N, int K)
{
    constexpr int IT = BMT / 32;
    constexpr int JT = BNT / 32;
    constexpr int AU = BMT / 64;
    constexpr int BU = BNT / 64;
    __shared__ _Float16 AhS[BMT * 32];
    __shared__ _Float16 BhS[BNT * 32];

    const int tid = threadIdx.x;
    const int w = tid >> 6;
    const int lane = tid & 63;
    const int l15 = lane & 15;
    const int quad = lane >> 4;
    const int wm = w >> 1, wn = w & 1;
    const int bm = blockIdx.y * BMT;
    const int bn = blockIdx.x * BNT;

    f32x4 acc[IT][JT];
    #pragma unroll
    for (int i = 0; i < IT; ++i)
        #pragma unroll
        for (int j = 0; j < JT; ++j)
            acc[i][j] = (f32x4){0.f, 0.f, 0.f, 0.f};

    h16x8 rah[AU], rbh[BU];
    auto loadg = [&](int k0) {
        #pragma unroll
        for (int u = 0; u < AU; ++u) {
            int c = tid + u * 256, m = c >> 2, kg = c & 3;
            rah[u] = *(const h16x8*)(Ah + (size_t)(bm + m) * K + k0 + kg * 8);
        }
        #pragma unroll
        for (int u = 0; u < BU; ++u) {
            int c = tid + u * 256, m = c >> 2, kg = c & 3;
            rbh[u] = *(const h16x8*)(Bh + (size_t)(bn + m) * K + k0 + kg * 8);
        }
    };

    loadg(0);
    for (int k0 = 0; k0 < K; k0 += 32) {
        __syncthreads();
        #pragma unroll
        for (int u = 0; u < AU; ++u) {
            int c = tid + u * 256, m = c >> 2, kg = c & 3;
            *(h16x8*)&AhS[LDSA(m, kg)] = rah[u];
        }
        #pragma unroll
        for (int u = 0; u < BU; ++u) {
            int c = tid + u * 256, m = c >> 2, kg = c & 3;
            *(h16x8*)&BhS[LDSA(m, kg)] = rbh[u];
        }
        __syncthreads();
        if (k0 + 32 < K) loadg(k0 + 32);

        h16x8 af[IT], bf[JT];
        #pragma unroll
        for (int i = 0; i < IT; ++i) {
            int m = wm * (BMT / 2) + i * 16 + l15;
            af[i] = *(h16x8*)&AhS[LDSA(m, quad)];
        }
        #pragma unroll
        for (int j = 0; j < JT; ++j) {
            int n = wn * (BNT / 2) + j * 16 + l15;
            bf[j] = *(h16x8*)&BhS[LDSA(n, quad)];
        }
        #pragma unroll
        for (int i = 0; i < IT; ++i)
            #pragma unroll
            for (int j = 0; j < JT; ++j)
                acc[i][j] = __builtin_amdgcn_mfma_f32_16x16x32_f16(af[i], bf[j], acc[i][j], 0, 0, 0);
    }

    #pragma unroll
    for (int j = 0; j < JT; ++j) {
        int col = bn + wn * (BNT / 2) + j * 16 + l15;
        float bb = bias[col];
        #pragma unroll
        for (int i = 0; i < IT; ++i)
            #pragma unroll
            for (int r = 0; r < 4; ++r) {
                int row = bm + wm * (BMT / 2) + i * 16 + quad * 4 + r;
                C[(size_t)row * N + col] = acc[i][j][r] + bb;
            }
    }
}

// ---------------- RoPE + scatter -> bf16 q (pre-scaled), k, v ----------------
__global__ __launch_bounds__(256) void rope_scatter_bf16(
    const float* __restrict__ qkv, const float* __restrict__ rpe,
    short* __restrict__ q, short* __restrict__ k, short* __restrict__ v)
{
    __shared__ float cs[40], sn[40];
    const int s = blockIdx.x;
    if (threadIdx.x < 40)
        __sincosf(rpe[s * 40 + threadIdx.x], &sn[threadIdx.x], &cs[threadIdx.x]);
    __syncthreads();
    const float scale = 0.11180339887498949f;  // 80^-0.5
    for (int j = threadIdx.x; j < ND3; j += 256) {
        int p = j / DD;
        int rem = j - p * DD;
        int hh = rem / HDD;
        int d = rem - hh * HDD;
        float x = qkv[(size_t)s * ND3 + j];
        float val;
        if (p == 2) {
            val = x;
        } else {
            int dm = (d < 40) ? d : d - 40;
            float other = (d < 40)
                ? -qkv[(size_t)s * ND3 + p * DD + hh * HDD + d + 40]
                :  qkv[(size_t)s * ND3 + p * DD + hh * HDD + d - 40];
            val = x * cs[dm] + other * sn[dm];
            if (p == 0) val *= scale;
        }
        short* dst = (p == 0) ? q : (p == 1) ? k : v;
        dst[((size_t)hh * SS + s) * HDD + d] = f2bf(val);
    }
}

// ------- flash attention v2: 32 q-rows/wave, XOR-swizzled Vts, fixed-max ------
// Block = 4 waves x 32 rows = 128 q-rows. Vts[d][key]: key-octet g stored at
// (g ^ (d&7)) -> transposed 8B staging writes and b128 reads are <=2-way (free).
__global__ __launch_bounds__(256) void attn_mfma(
    const short* __restrict__ q, const short* __restrict__ k,
    const short* __restrict__ v, float* __restrict__ o_part,
    float* __restrict__ l_part)
{
    __shared__ short Ks[64][104];     // keys x dims (pad cols 80..95 zeroed)
    __shared__ short Vts[80 * 64];    // dims x keys, XOR-swizzled octets
    __shared__ short Ps[4][32][72];   // per-wave P tile: 32 rows x 64 keys

    const int h = blockIdx.y;
    const int q0 = blockIdx.x << 7;   // 128 rows per block
    const int z = blockIdx.z;
    const int tid = threadIdx.x;
    const int w = tid >> 6;
    const int lane = tid & 63;
    const int l15 = lane & 15;
    const int quad = lane >> 4;

    const short* qbase = q + (size_t)h * SS * HDD;
    const short* kbase = k + (size_t)h * SS * HDD;
    const short* vbase = v + (size_t)h * SS * HDD;

    // Q fragments: 2 row-groups x 3 k-chunks
    short8 qf[2][3];
    #pragma unroll
    for (int i = 0; i < 2; ++i) {
        const int row = q0 + w * 32 + i * 16 + l15;
        #pragma unroll
        for (int kk = 0; kk < 3; ++kk) {
            int c0 = kk * 32 + quad * 8;
            qf[i][kk] = (c0 < HDD) ? *(const short8*)(qbase + (size_t)row * HDD + c0)
                                   : (short8)0;
        }
    }

    if (tid < 128) {   // zero K pad cols 80..95
        int r = tid >> 1, c = 80 + (tid & 1) * 8;
        *(short8*)&Ks[r][c] = (short8)0;
    }

    float lsum[2][4] = {{0.f}};
    f32x4 o[2][5];
    #pragma unroll
    for (int i = 0; i < 2; ++i)
        #pragma unroll
        for (int n = 0; n < 5; ++n) o[i][n] = (f32x4){0.f, 0.f, 0.f, 0.f};

    const int kt0 = z << 10;
    for (int kt = kt0; kt < kt0 + 1024; kt += 64) {
        __syncthreads();
        // ---- stage K tile (coalesced b128, natural layout) ----
        #pragma unroll
        for (int u = 0; u < 3; ++u) {
            int i = tid + u * 256;
            if (i < 640) {
                int r = i / 10, c = (i - r * 10) * 8;
                *(short8*)&Ks[r][c] = *(const short8*)(kbase + (size_t)(kt + r) * HDD + c);
            }
        }
        // ---- stage V transposed into swizzled Vts ----
        #pragma unroll
        for (int u = 0; u < 2; ++u) {
            int task = tid + u * 256;
            if (task < 320) {
                int r4 = (task & 15) << 2;        // key base (0,4,..60)
                int d4 = (task >> 4) << 2;        // dim base (0,4,..76)
                s16x4 a0 = *(const s16x4*)(vbase + (size_t)(kt + r4 + 0) * HDD + d4);
                s16x4 a1 = *(const s16x4*)(vbase + (size_t)(kt + r4 + 1) * HDD + d4);
                s16x4 a2 = *(const s16x4*)(vbase + (size_t)(kt + r4 + 2) * HDD + d4);
                s16x4 a3 = *(const s16x4*)(vbase + (size_t)(kt + r4 + 3) * HDD + d4);
                #pragma unroll
                for (int j = 0; j < 4; ++j) {
                    s16x4 w4 = {a0[j], a1[j], a2[j], a3[j]};
                    int d = d4 + j;
                    int sw = (r4 >> 3) ^ (d & 7);
                    *(s16x4*)&Vts[d * 64 + sw * 8 + (r4 & 7)] = w4;
                }
            }
        }
        __syncthreads();

        // ---- QK^T: 24 MFMAs on 12 shared K-frag reads ----
        f32x4 s_[2][4];
        #pragma unroll
        for (int nt = 0; nt < 4; ++nt) {
            short8 bf0 = *(short8*)&Ks[nt * 16 + l15][0 * 32 + quad * 8];
            short8 bf1 = *(short8*)&Ks[nt * 16 + l15][1 * 32 + quad * 8];
            short8 bf2 = *(short8*)&Ks[nt * 16 + l15][2 * 32 + quad * 8];
            #pragma unroll
            for (int i = 0; i < 2; ++i) {
                f32x4 acc = (f32x4){0.f, 0.f, 0.f, 0.f};
                acc = __builtin_amdgcn_mfma_f32_16x16x32_bf16(qf[i][0], bf0, acc, 0, 0, 0);
                acc = __builtin_amdgcn_mfma_f32_16x16x32_bf16(qf[i][1], bf1, acc, 0, 0, 0);
                acc = __builtin_amdgcn_mfma_f32_16x16x32_bf16(qf[i][2], bf2, acc, 0, 0, 0);
                s_[i][nt] = acc;
            }
        }

        // ---- p = exp(s - 16), partial sums, P -> LDS ----
        #pragma unroll
        for (int i = 0; i < 2; ++i)
            #pragma unroll
            for (int nt = 0; nt < 4; ++nt)
                #pragma unroll
                for (int r = 0; r < 4; ++r) {
                    float p = __expf(s_[i][nt][r] - 16.f);
                    lsum[i][r] += p;
                    Ps[w][i * 16 + quad * 4 + r][nt * 16 + l15] = f2bf(p);
                }

        // ---- P -> A-operand, PV: 20 MFMAs on 10 shared V-frag reads ----
        short8 pf[2][2];
        #pragma unroll
        for (int i = 0; i < 2; ++i)
            #pragma unroll
            for (int kk = 0; kk < 2; ++kk)
                pf[i][kk] = *(short8*)&Ps[w][i * 16 + l15][kk * 32 + quad * 8];
        #pragma unroll
        for (int n = 0; n < 5; ++n) {
            #pragma unroll
            for (int kk = 0; kk < 2; ++kk) {
                int d = n * 16 + l15;
                int sw = (kk * 4 + quad) ^ (l15 & 7);
                short8 vf = *(short8*)&Vts[d * 64 + sw * 8];
                #pragma unroll
                for (int i = 0; i < 2; ++i)
                    o[i][n] = __builtin_amdgcn_mfma_f32_16x16x32_bf16(pf[i][kk], vf, o[i][n], 0, 0, 0);
            }
        }
    }

    // ---- deferred l-reduction + stores ----
    float* ob = o_part + (size_t)z * SS * DD;
    #pragma unroll
    for (int i = 0; i < 2; ++i) {
        #pragma unroll
        for (int r = 0; r < 4; ++r) {
            float rs = lsum[i][r];
            #pragma unroll
            for (int off = 1; off < 16; off <<= 1)
                rs += __shfl_xor(rs, off, 64);
            lsum[i][r] = rs;
        }
        #pragma unroll
        for (int n = 0; n < 5; ++n)
            #pragma unroll
            for (int r = 0; r < 4; ++r) {
                int row = q0 + w * 32 + i * 16 + quad * 4 + r;
                ob[(size_t)row * DD + h * HDD + n * 16 + l15] = o[i][n][r];
            }
        if (l15 == 0)
            #pragma unroll
            for (int r = 0; r < 4; ++r)
                l_part[((size_t)z * HH + h) * SS + q0 + w * 32 + i * 16 + quad * 4 + r] = lsum[i][r];
    }
}

// ---------------- merge K-split halves, emit fp16 ----------------
__global__ __launch_bounds__(256) void attn_merge(
    const float* __restrict__ o_part, const float* __restrict__ l_part,
    _Float16* __restrict__ oh)
{
    int i = (blockIdx.x * 256 + threadIdx.x) * 4;
    int row = i / DD;
    int col = i - row * DD;
    int h = col / HDD;
    float4 a = *(const float4*)(o_part + i);
    float4 b = *(const float4*)(o_part + (size_t)SS * DD + i);
    float l = l_part[h * SS + row] + l_part[(HH + h) * SS + row];
    float inv = 1.f / l;
    h16x4 hv;
    hv[0] = (_Float16)((a.x + b.x) * inv);
    hv[1] = (_Float16)((a.y + b.y) * inv);
    hv[2] = (_Float16)((a.z + b.z) * inv);
    hv[3] = (_Float16)((a.w + b.w) * inv);
    *(h16x4*)(oh + i) = hv;
}

extern "C" void kernel_launch(void* const* d_in, const int* in_sizes, int n_in,
                              void* d_out, int out_size, void* d_ws, size_t ws_size,
                              hipStream_t stream)
{
    const float* hs     = (const float*)d_in[0];
    const float* rpe    = (const float*)d_in[1];
    const float* qkv_w  = (const float*)d_in[2];
    const float* qkv_b  = (const float*)d_in[3];
    const float* proj_w = (const float*)d_in[4];
    const float* proj_b = (const float*)d_in[5];
    float* out = (float*)d_out;

    // ---- workspace layout (52.4 MB, region-aliased; 2-byte units) ----
    short* s0 = (short*)d_ws;                 // R0: 15,728,640 units
    float* qkv_f  = (float*)d_ws;             //   [S][3D] fp32, dead after rope
    float* o_part = (float*)d_ws;             //   R0 reuse after rope: 2 x S x D
    float* l_part = (float*)d_ws + 5242880;   //   2 x H x S partial l
    short* s1 = s0 + 15728640;                // R1: 7,864,320 units
    _Float16* qkvw_h = (_Float16*)s1;         //   4,915,200 (dead after gemm1)
    short* qb = s1;                           //   R1 reuse after gemm1
    short* kb = s1 + 2621440;
    short* vb = s1 + 5242880;
    _Float16* attn_h = (_Float16*)s1;         //   R1 reuse after attn (aliases qb)
    short* s2 = s1 + 7864320;                 // R2: 2,621,440 units
    _Float16* hs_h = (_Float16*)s2;           //   dead after gemm1
    _Float16* projw_h = (_Float16*)s2;        //   R2 reuse after gemm1

    const int n_hs = SS * DD;        // 2,621,440 -> 2560 blocks
    const int n_qw = ND3 * DD;       // 4,915,200 -> 4800 blocks
    const int n_pw = DD * DD;        // 1,638,400 -> 1600 blocks

    split_f16<<<n_hs / 1024 + n_qw / 1024, 256, 0, stream>>>(
        hs, hs_h, n_hs / 1024,
        qkv_w, qkvw_h, n_qw / 1024,
        qkv_w, qkvw_h);   // third slot unused
    // QKV GEMM: 128x128 tiles, grid (30, 16) = 480 blocks
    gemm_f16<128, 128><<<dim3(ND3 / 128, SS / 128), 256, 0, stream>>>(
        hs_h, qkvw_h, qkv_b, qkv_f, SS, ND3, DD);
    // proj_w -> fp16 into R2 (hs_h dead after gemm1)
    split_f16<<<n_pw / 1024, 256, 0, stream>>>(
        proj_w, projw_h, n_pw / 1024,
        proj_w, projw_h, 0,
        proj_w, projw_h);
    rope_scatter_bf16<<<SS, 256, 0, stream>>>(qkv_f, rpe, qb, kb, vb);
    attn_mfma<<<dim3(SS / 128, HH, 2), 256, 0, stream>>>(qb, kb, vb, o_part, l_part);
    attn_merge<<<(SS * DD) / 1024, 256, 0, stream>>>(o_part, l_part, attn_h);
    // proj GEMM: 64x128 tiles, grid (10, 32) = 320 blocks
    gemm_f16<64, 128><<<dim3(DD / 128, SS / 64), 256, 0, stream>>>(
        attn_h, projw_h, proj_b, out, SS, DD, DD);
}